// Round 4
// baseline (399.965 us; speedup 1.0000x reference)
//
#include <hip/hip_runtime.h>
#include <stdint.h>

// Problem constants (reference: M,K,N = 8192,4096,4096)
#define M_DIM 8192
#define K_DIM 4096
#define N_DIM 4096

typedef __attribute__((ext_vector_type(4)))  int v4i;
typedef __attribute__((ext_vector_type(16))) int v16i;

// ---------------------------------------------------------------------------
// Phase 1: pack int32 (harness-normalized int8 values in [-127,127]) -> int8.
// One thread = one v4i load (16 B/lane) + one dword store. Known-good.
// ---------------------------------------------------------------------------
__device__ __forceinline__ int pack4(v4i v) {
    return (int)(((uint32_t)v.x & 0xffu)
               | (((uint32_t)v.y & 0xffu) << 8)
               | (((uint32_t)v.z & 0xffu) << 16)
               | (((uint32_t)v.w & 0xffu) << 24));
}

__global__ __launch_bounds__(256) void pack_ab(
    const int* __restrict__ srcA, const int* __restrict__ srcB,
    int* __restrict__ dstA, int* __restrict__ dstB,
    int aGroups)
{
    int g = blockIdx.x * 256 + threadIdx.x;
    const v4i* src;
    int* dst;
    if (g < aGroups) { src = (const v4i*)srcA; dst = dstA; }
    else             { src = (const v4i*)srcB; dst = dstB; g -= aGroups; }
    dst[g] = pack4(src[g]);
}

// ---------------------------------------------------------------------------
// Async global->LDS, 16B per lane. LDS dest = wave-uniform base + lane*16
// (m104/m108); swizzled layouts realized by pre-swizzling the GLOBAL source.
// ---------------------------------------------------------------------------
__device__ __forceinline__ void gload16(const void* g, void* lds_p) {
    __builtin_amdgcn_global_load_lds(
        (__attribute__((address_space(1))) void*)(g),
        (__attribute__((address_space(3))) void*)(lds_p),
        16, 0, 0);
}

// ---------------------------------------------------------------------------
// Phase 2: 256x256 tile, BK=128, 8 waves (2M x 4N), 8-phase schedule,
// counted vmcnt, XOR bank-swizzle, setprio, XCD swizzle.
// ROUND 4 CHANGE: mfma_i32_32x32x32_i8 (was 16x16x64).
//   +11.7% MFMA ceiling (4404 vs 3944 TOPS, m55/m16); MFMA inst count
//   halves (32 vs 64 per K-tile per wave) at identical ds_read bytes.
// LDS layout/staging/swizzle/vmcnt/phase schedule IDENTICAL to R3
// (verified absmax 2.4e-4): phases relabel (ksh,qm)->(ksh,kc).
// Per phase: 4 A-frag + 2 B-frag ds_read_b128 (uniform) + 8 MFMA.
//
// Conflict-freedom of 32-row fragment reads under swizzle cg=sc^((row>>1)&3):
// an 8-lane HW group (8 consecutive rows r) hits bank-group 16(r&1)+4c with
// c = g ^ ((r>>1)&3); the 8 (r&1, (r>>1)&3) combos are distinct -> 8 disjoint
// 4-bank groups = all 32 banks. Same derivation that measured 0 conflicts
// for the 16-row reads in R1-R3.
//
// Stage->read / WAR distances: unchanged from R3 (see R3 header audit).
// vmcnt: WAIT4 at p4 (certifies buf1.ks0 staged prev p7,p8 + buf1.ks1 from
// p1,p2) and p8 (certifies buf0.ks0 from p3,p4 + buf0.ks1 from p5,p6).
// Never vmcnt(0) in the main loop.
// ---------------------------------------------------------------------------
__global__ __launch_bounds__(512, 2) void int8_gemm_dequant(
    const int8_t* __restrict__ A,        // [M,K] int8 packed
    const float*  __restrict__ scale_x,  // [M]
    const int8_t* __restrict__ W,        // [N,K] int8 packed
    const float*  __restrict__ scale_w,  // [N]
    const float*  __restrict__ bias,     // [N] (harness-normalized fp16->f32)
    float*        __restrict__ out)      // [M,N] f32
{
    __shared__ __align__(16) int8_t lds[131072];   // 128 KiB

    const int t    = threadIdx.x;          // 0..511
    const int lane = t & 63;
    const int w    = t >> 6;               // wave 0..7
    const int wm   = w >> 2;               // 0..1  (M half: 128 rows)
    const int wn   = w & 3;                // 0..3  (N quarter: 64 cols)

    // Bijective XCD swizzle (512 % 8 == 0): each XCD gets 4x16 tile chunk.
    const int wg  = blockIdx.x;
    const int swz = (wg & 7) * 64 + (wg >> 3);
    const int n0  = (swz & 15) * 256;
    const int m0  = (swz >> 4) * 256;

    // Staging: thread t owns slots t and t+512 of each 16 KB half.
    // slot s -> row = s>>2, sc = s&3, global k-granule cg = sc ^ ((s>>3)&3).
    const int srow = t >> 2;                        // 0..127 (2nd load: +128)
    const int scg  = (t & 3) ^ ((t >> 3) & 3);      // same for slot t+512
    const int8_t* Ap = A + (size_t)(m0 + srow) * K_DIM + scg * 16;
    const int8_t* Bp = W + (size_t)(n0 + srow) * K_DIM + scg * 16;
    int8_t* ldsb = &lds[t * 16];

    // 32x32x32 fragment read: lane reads row (base32 + (lane&31)), k-granule
    // g2 = (kc<<1)|(lane>>5); swizzled col = g2 ^ ((lane>>1)&3) (base rows
    // are multiples of 32, so the row-swizzle bits reduce to lane bits).
    // kc flips addr bit 5: addr = base + (rdb ^ (kc*32)).
    const int rdb = (lane & 31) * 64 + ((((lane >> 5) ^ ((lane >> 1) & 3))) * 16);

    v16i acc[4][2] = {};                   // [mt 32-row block][nt 32-col block]
    // Double-buffered fragment sets (all indices compile-time, rule #20).
    v4i a0[4], a1[4], b0[2], b1[2];

#define HOFF(buf, mat, ksh) ((((buf) << 2) | ((mat) << 1) | (ksh)) << 14)

#define STAGE(buf, mat, ksh, OFF) do {                                        \
    const int8_t* _g = ((mat) ? Bp : Ap) + (OFF) + (ksh) * 64;                \
    int8_t* _d = ldsb + HOFF(buf, mat, ksh);                                  \
    gload16(_g, _d);                                                          \
    gload16(_g + (size_t)128 * K_DIM, _d + 8192);                             \
} while (0)

// Read the 6 fragments (4 A + 2 B) for (buf, ksh, kc) into sets AS/BS.
#define READ_F(AS, BS, buf, ksh, kc) do {                                     \
    const int8_t* _pa = lds + HOFF(buf, 0, ksh) + wm * 8192                   \
                        + (rdb ^ ((kc) * 32));                                \
    AS[0] = *(const v4i*)(_pa);                                               \
    AS[1] = *(const v4i*)(_pa + 2048);                                        \
    AS[2] = *(const v4i*)(_pa + 4096);                                        \
    AS[3] = *(const v4i*)(_pa + 6144);                                        \
    const int8_t* _pb = lds + HOFF(buf, 1, ksh) + wn * 4096                   \
                        + (rdb ^ ((kc) * 32));                                \
    BS[0] = *(const v4i*)(_pb);                                               \
    BS[1] = *(const v4i*)(_pb + 2048);                                        \
} while (0)

#define MFMA_C(AF, BF) do {                                                   \
    _Pragma("unroll")                                                         \
    for (int mt = 0; mt < 4; ++mt) {                                          \
        _Pragma("unroll")                                                     \
        for (int nt = 0; nt < 2; ++nt) {                                      \
            acc[mt][nt] = __builtin_amdgcn_mfma_i32_32x32x32_i8(              \
                AF[mt], BF[nt], acc[mt][nt], 0, 0, 0);                        \
        }                                                                     \
    }                                                                         \
} while (0)

#define NOWAIT ((void)0)
#define WAIT4  asm volatile("s_waitcnt vmcnt(4)" ::: "memory")
#define WAIT0  asm volatile("s_waitcnt vmcnt(0)" ::: "memory")
#define NOSTG  ((void)0)
#define NORD   ((void)0)

// Phase: stage (vmem issue) -> [counted vmcnt] -> barrier -> issue NEXT
// phase's ds_reads -> sched fence -> MFMA current frags (read one phase ago).
#define PH(AF, BF, NEXTRD, STG, WAITV) do {                                   \
    STG;                                                                      \
    WAITV;                                                                    \
    __builtin_amdgcn_s_barrier();                                             \
    NEXTRD;                                                                   \
    __builtin_amdgcn_sched_barrier(0);                                        \
    __builtin_amdgcn_s_setprio(1);                                            \
    MFMA_C(AF, BF);                                                           \
    __builtin_amdgcn_s_setprio(0);                                            \
} while (0)

    // Prologue: tile0 full (8 loads) + tile1 ks0 (4 loads); drain tile0,
    // leave tile1.ks0's 4 in flight. Pre-read phase-1 fragments.
    STAGE(0, 1, 0, 0);   STAGE(0, 0, 0, 0);
    STAGE(0, 1, 1, 0);   STAGE(0, 0, 1, 0);
    STAGE(1, 1, 0, 128); STAGE(1, 0, 0, 128);
    WAIT4;
    __builtin_amdgcn_s_barrier();
    READ_F(a0, b0, 0, 0, 0);

    // Main loop: i = 0..14; Ap/Bp advance 256 B/iter; stage offsets are
    // immediates: T1 = +128, T2 = +256, T3 = +384 (ksh adds 64).
    // Phase p computes (buf,ksh,kc); RD(p) fetches p+1's frags:
    //  p1:(0,0,0) p2:(0,0,1) p3:(0,1,0) p4:(0,1,1)
    //  p5:(1,0,0) p6:(1,0,1) p7:(1,1,0) p8:(1,1,1)
    for (int i = 0; i < 15; ++i) {
        PH(a0, b0, READ_F(a1, b1, 0, 0, 1), STAGE(1, 1, 1, 128), NOWAIT); // p1
        PH(a1, b1, READ_F(a0, b0, 0, 1, 0), STAGE(1, 0, 1, 128), NOWAIT); // p2
        PH(a0, b0, READ_F(a1, b1, 0, 1, 1), STAGE(0, 1, 0, 256), NOWAIT); // p3
        PH(a1, b1, READ_F(a0, b0, 1, 0, 0), STAGE(0, 0, 0, 256), WAIT4);  // p4
        PH(a0, b0, READ_F(a1, b1, 1, 0, 1), STAGE(0, 1, 1, 256), NOWAIT); // p5
        PH(a1, b1, READ_F(a0, b0, 1, 1, 0), STAGE(0, 0, 1, 256), NOWAIT); // p6
        PH(a0, b0, READ_F(a1, b1, 1, 1, 1), STAGE(1, 1, 0, 384), NOWAIT); // p7
        PH(a1, b1, READ_F(a0, b0, 0, 0, 0), STAGE(1, 0, 0, 384), WAIT4);  // p8
        Ap += 256; Bp += 256;
    }

    // Peeled final iteration (tiles 30,31): finish staging tile31.ks1, full
    // drain once (WAIT0 certifies T31 before p4's just-in-time reads).
    PH(a0, b0, READ_F(a1, b1, 0, 0, 1), STAGE(1, 1, 1, 128), NOWAIT);
    PH(a1, b1, READ_F(a0, b0, 0, 1, 0), STAGE(1, 0, 1, 128), NOWAIT);
    PH(a0, b0, READ_F(a1, b1, 0, 1, 1), NOSTG, NOWAIT);
    PH(a1, b1, READ_F(a0, b0, 1, 0, 0), NOSTG, WAIT0);
    PH(a0, b0, READ_F(a1, b1, 1, 0, 1), NOSTG, NOWAIT);
    PH(a1, b1, READ_F(a0, b0, 1, 1, 0), NOSTG, NOWAIT);
    PH(a0, b0, READ_F(a1, b1, 1, 1, 1), NOSTG, NOWAIT);
    PH(a1, b1, NORD, NOSTG, NOWAIT);

    // Epilogue: dequant + bias. 32x32 C/D layout (dtype-independent,
    // m74/m101): col = lane&31, row = (reg&3) + 8*(reg>>2) + 4*(lane>>5).
    const int colL = lane & 31;
    const int rhi  = (lane >> 5) * 4;
    const float inv127sq = 1.0f / (127.0f * 127.0f);
    const int mbase = m0 + wm * 128;
    const int nbase = n0 + wn * 64;

    const int   nA = nbase + colL;
    const int   nB = nbase + 32 + colL;
    const float swA = scale_w[nA] * inv127sq;
    const float swB = scale_w[nB] * inv127sq;
    const float bfA = bias[nA];
    const float bfB = bias[nB];

#pragma unroll
    for (int mt = 0; mt < 4; ++mt) {
#pragma unroll
        for (int reg = 0; reg < 16; ++reg) {
            const int row = mbase + mt * 32 + (reg & 3) + 8 * (reg >> 2) + rhi;
            const float s = scale_x[row];
            float* orow = out + (size_t)row * N_DIM;
            orow[nA] = (float)acc[mt][0][reg] * s * swA + bfA;
            orow[nB] = (float)acc[mt][1][reg] * s * swB + bfB;
        }
    }

#undef HOFF
#undef STAGE
#undef READ_F
#undef MFMA_C
#undef NOWAIT
#undef WAIT4
#undef WAIT0
#undef NOSTG
#undef NORD
#undef PH
}

extern "C" void kernel_launch(void* const* d_in, const int* in_sizes, int n_in,
                              void* d_out, int out_size, void* d_ws, size_t ws_size,
                              hipStream_t stream) {
    // Harness normalization: integer inputs -> int32, fp16 -> f32.
    const int*   x_i32   = (const int*)  d_in[0];   // [M,K] as int32
    const float* scale_x = (const float*)d_in[1];   // [M] f32
    const int*   w_i32   = (const int*)  d_in[2];   // [N,K] as int32
    const float* scale_w = (const float*)d_in[3];   // [N] f32
    const float* bias    = (const float*)d_in[4];   // [N] f32 (from fp16)
    float* out = (float*)d_out;                     // [M,N] f32

    // Scratch layout: packed A8 then B8.
    int8_t* A8 = (int8_t*)d_ws;                          // 33,554,432 B
    int8_t* B8 = A8 + (size_t)M_DIM * K_DIM;             // 16,777,216 B

    const int a_groups = (M_DIM * K_DIM) / 4;            // 8,388,608
    const int b_groups = (N_DIM * K_DIM) / 4;            // 4,194,304
    const int total    = a_groups + b_groups;            // 12,582,912 (÷256)
    pack_ab<<<total / 256, 256, 0, stream>>>(x_i32, w_i32, (int*)A8, (int*)B8,
                                             a_groups);

    // 256x256 tiles: grid = (8192/256)*(4096/256) = 32*16 = 512 blocks.
    int8_gemm_dequant<<<512, 512, 0, stream>>>(A8, scale_x, B8, scale_w, bias, out);
}